// Round 13
// baseline (404.219 us; speedup 1.0000x reference)
//
#include <hip/hip_runtime.h>
#include <math.h>

#define D 64
#define NUM_USERS 100000
#define NUM_ITEMS 50000
#define N_NODES 150000   // NUM_USERS + NUM_ITEMS
#define NNZ 2400000
#define BATCH 8192
#define NEG_SLOPE 0.1f
#define EPS_NRM 1e-12f

// bucket geometry: bucket = row >> 8 (256 rows/bucket)
#define NBUCKET 586                 // ceil(150000/256)
#define NCHUNK  256
#define CH      9375                // NNZ / 256 exactly
#define NH      (NBUCKET * NCHUNK)  // 150016
#define NBH     (NH / 256)          // 586 scan blocks
#define CAP     6144                // LDS sorted-buffer capacity (mean 4096, ~32 sigma)
#define KPT     6                   // per-thread reg cache: ceil(CAP/1024)

typedef unsigned short ushort_t;

__device__ __forceinline__ float wave_sum64(float v) {
    #pragma unroll
    for (int off = 32; off > 0; off >>= 1)
        v += __shfl_xor(v, off, 64);
    return v;
}

__device__ __forceinline__ int wave_sum64_i(int v) {
    #pragma unroll
    for (int off = 32; off > 0; off >>= 1)
        v += __shfl_xor(v, off, 64);
    return v;
}

__device__ __forceinline__ float bf2f(ushort_t u) {
    return __uint_as_float(((unsigned)u) << 16);
}
__device__ __forceinline__ ushort_t f2bf(float f) {
    unsigned x = __float_as_uint(f);
    unsigned r = (x + 0x7FFFu + ((x >> 16) & 1u)) >> 16;   // RNE
    return (ushort_t)r;
}

// ---------- CSR build: 2-level bucket sort, LDS int atomics only ----------

__global__ void bucket_hist(const int* __restrict__ rows, int* __restrict__ ht) {
    __shared__ int hist[NBUCKET];
    int c = blockIdx.x, tid = threadIdx.x;
    for (int b = tid; b < NBUCKET; b += 256) hist[b] = 0;
    __syncthreads();
    int base = c * CH;
    for (int i = tid; i < CH; i += 256)
        atomicAdd(&hist[rows[base + i] >> 8], 1);
    __syncthreads();
    for (int b = tid; b < NBUCKET; b += 256) ht[b * NCHUNK + c] = hist[b];
}

__global__ void scan1_kernel(const int* __restrict__ in, int* __restrict__ out,
                             int* __restrict__ bsums, int n) {
    int tid = threadIdx.x, gid = blockIdx.x * 256 + tid;
    int v = (gid < n) ? in[gid] : 0;
    int lane = tid & 63, w = tid >> 6;
    int s = v;
    #pragma unroll
    for (int off = 1; off < 64; off <<= 1) {
        int t = __shfl_up(s, off, 64);
        if (lane >= off) s += t;
    }
    __shared__ int wsum[4];
    if (lane == 63) wsum[w] = s;
    __syncthreads();
    if (tid == 0) {
        int a = 0;
        #pragma unroll
        for (int i = 0; i < 4; i++) { int t = wsum[i]; wsum[i] = a; a += t; }
    }
    __syncthreads();
    int incl = s + wsum[w];
    if (gid < n) out[gid] = incl - v;           // exclusive
    if (tid == 255) bsums[blockIdx.x] = incl;   // block total (unscanned)
}

// fused: each block reduces bsums[0..b) itself, then adds to its 256 elems
__global__ void scan3_kernel(int* __restrict__ out, const int* __restrict__ bsums, int n) {
    __shared__ int wtot[4];
    __shared__ int total;
    int b = blockIdx.x, tid = threadIdx.x;
    int lane = tid & 63, w = tid >> 6;
    int partial = 0;
    for (int i = tid; i < b; i += 256) partial += bsums[i];
    partial = wave_sum64_i(partial);
    if (lane == 0) wtot[w] = partial;
    __syncthreads();
    if (tid == 0) total = wtot[0] + wtot[1] + wtot[2] + wtot[3];
    __syncthreads();
    int gid = b * 256 + tid;
    if (gid < n) out[gid] += total;
}

__global__ void __launch_bounds__(512) bucket_scatter(
        const int* __restrict__ rows, const int* __restrict__ cols,
        const float* __restrict__ vals, const int* __restrict__ hoff,
        int2* __restrict__ est) {
    __shared__ int cur[NBUCKET];
    int c = blockIdx.x, tid = threadIdx.x;
    for (int b = tid; b < NBUCKET; b += 512) cur[b] = hoff[b * NCHUNK + c];
    __syncthreads();
    int base = c * CH;
    for (int i = tid; i < CH; i += 512) {
        int e = base + i;
        int r = rows[e];
        int pos = atomicAdd(&cur[r >> 8], 1);          // LDS int atomic
        est[pos] = make_int2(cols[e] | ((r & 255) << 18), __float_as_int(vals[e]));
    }
}

// one block per bucket: single est read (register-cached), LDS hist + scan,
// scatter from registers into sorted LDS buffer, coalesced dump. rowptr direct.
__global__ void __launch_bounds__(1024) bucket_sort(const int2* __restrict__ est,
                                                    const int* __restrict__ hoff,
                                                    int2* __restrict__ es,
                                                    int* __restrict__ rowptr) {
    __shared__ int  hist[256];
    __shared__ int  wsum[4];
    __shared__ int2 outbuf[CAP];    // 48 KB
    int b = blockIdx.x, tid = threadIdx.x;
    int beg = hoff[b * NCHUNK];
    int end = (b == NBUCKET - 1) ? NNZ : hoff[(b + 1) * NCHUNK];
    if (tid < 256) hist[tid] = 0;
    __syncthreads();
    // pass 1: read est ONCE into registers, build hist
    int2 kv[KPT];
    int  cnt = 0;
    for (int i = beg + tid; i < end && cnt < KPT; i += 1024) {
        int2 k = est[i];
        kv[cnt++] = k;
        atomicAdd(&hist[k.x >> 18], 1);
    }
    __syncthreads();
    int excl = 0;
    if (tid < 256) {
        int v = hist[tid];
        int lane = tid & 63, w = tid >> 6;
        int s = v;
        #pragma unroll
        for (int off = 1; off < 64; off <<= 1) {
            int t = __shfl_up(s, off, 64);
            if (lane >= off) s += t;
        }
        if (lane == 63) wsum[w] = s;
        excl = s - v;
    }
    __syncthreads();
    if (tid == 0) {
        int a = 0;
        #pragma unroll
        for (int i = 0; i < 4; i++) { int t = wsum[i]; wsum[i] = a; a += t; }
    }
    __syncthreads();
    if (tid < 256) {
        excl += wsum[tid >> 6];
        int r = (b << 8) + tid;
        if (r <= N_NODES) rowptr[r] = beg + excl;
        hist[tid] = excl;           // reuse as cursor (bucket-relative)
    }
    __syncthreads();
    // pass 2: scatter from registers (no global re-read)
    for (int j = 0; j < cnt; j++) {
        int d = atomicAdd(&hist[kv[j].x >> 18], 1);        // LDS int atomic
        outbuf[d] = make_int2(kv[j].x & 0x3FFFF, kv[j].y); // LDS random write
    }
    __syncthreads();
    int n = end - beg;
    for (int i = tid; i < n; i += 1024)
        es[beg + i] = outbuf[i];                           // coalesced dump
}

// ---------- GCN ----------
__global__ void init_kernel(const float* __restrict__ upref,
                            const float* __restrict__ ipref,
                            ushort_t* __restrict__ p0) {
    int row  = blockIdx.x * 4 + (threadIdx.x >> 6);
    int lane = threadIdx.x & 63;
    if (row >= N_NODES) return;
    float x = (row < NUM_USERS) ? upref[(size_t)row * D + lane]
                                : ipref[(size_t)(row - NUM_USERS) * D + lane];
    x = (x >= 0.f) ? x : NEG_SLOPE * x;
    float norm = sqrtf(wave_sum64(x * x));
    float y = x / fmaxf(norm, EPS_NRM);
    p0[(size_t)row * D + lane] = f2bf(y);
}

// one wave per row; 8 edge-slots (sub = lane>>3), 8 features/lane (fl = lane&7);
// 2x unrolled (round-8 exact form: best measured 68.7-69.6 us/layer).
__global__ void gather_kernel(const int* __restrict__ rowptr,
                              const int2* __restrict__ es,
                              const ushort_t* __restrict__ p,
                              ushort_t* __restrict__ pn) {
    int row  = blockIdx.x * 4 + (threadIdx.x >> 6);
    int lane = threadIdx.x & 63;
    if (row >= N_NODES) return;
    int sub = lane >> 3;
    int fl  = lane & 7;
    int beg = rowptr[row], end = rowptr[row + 1];

    float a[8];
    #pragma unroll
    for (int k = 0; k < 8; k++) a[k] = 0.f;

    int e = beg + sub;
    while (e + 8 < end) {
        int2 cv0 = es[e];
        int2 cv1 = es[e + 8];
        float v0 = __int_as_float(cv0.y);
        float v1 = __int_as_float(cv1.y);
        const uint4 q0 = *(const uint4*)(p + ((unsigned)(cv0.x << 6) | (fl << 3)));
        const uint4 q1 = *(const uint4*)(p + ((unsigned)(cv1.x << 6) | (fl << 3)));
        a[0] = fmaf(v0, __uint_as_float(q0.x << 16),         a[0]);
        a[1] = fmaf(v0, __uint_as_float(q0.x & 0xFFFF0000u), a[1]);
        a[2] = fmaf(v0, __uint_as_float(q0.y << 16),         a[2]);
        a[3] = fmaf(v0, __uint_as_float(q0.y & 0xFFFF0000u), a[3]);
        a[4] = fmaf(v0, __uint_as_float(q0.z << 16),         a[4]);
        a[5] = fmaf(v0, __uint_as_float(q0.z & 0xFFFF0000u), a[5]);
        a[6] = fmaf(v0, __uint_as_float(q0.w << 16),         a[6]);
        a[7] = fmaf(v0, __uint_as_float(q0.w & 0xFFFF0000u), a[7]);
        a[0] = fmaf(v1, __uint_as_float(q1.x << 16),         a[0]);
        a[1] = fmaf(v1, __uint_as_float(q1.x & 0xFFFF0000u), a[1]);
        a[2] = fmaf(v1, __uint_as_float(q1.y << 16),         a[2]);
        a[3] = fmaf(v1, __uint_as_float(q1.y & 0xFFFF0000u), a[3]);
        a[4] = fmaf(v1, __uint_as_float(q1.z << 16),         a[4]);
        a[5] = fmaf(v1, __uint_as_float(q1.z & 0xFFFF0000u), a[5]);
        a[6] = fmaf(v1, __uint_as_float(q1.w << 16),         a[6]);
        a[7] = fmaf(v1, __uint_as_float(q1.w & 0xFFFF0000u), a[7]);
        e += 16;
    }
    if (e < end) {
        int2 cv = es[e];
        float v = __int_as_float(cv.y);
        const uint4 q = *(const uint4*)(p + ((unsigned)(cv.x << 6) | (fl << 3)));
        a[0] = fmaf(v, __uint_as_float(q.x << 16),         a[0]);
        a[1] = fmaf(v, __uint_as_float(q.x & 0xFFFF0000u), a[1]);
        a[2] = fmaf(v, __uint_as_float(q.y << 16),         a[2]);
        a[3] = fmaf(v, __uint_as_float(q.y & 0xFFFF0000u), a[3]);
        a[4] = fmaf(v, __uint_as_float(q.z << 16),         a[4]);
        a[5] = fmaf(v, __uint_as_float(q.z & 0xFFFF0000u), a[5]);
        a[6] = fmaf(v, __uint_as_float(q.w << 16),         a[6]);
        a[7] = fmaf(v, __uint_as_float(q.w & 0xFFFF0000u), a[7]);
    }

    #pragma unroll
    for (int k = 0; k < 8; k++) {
        a[k] += __shfl_xor(a[k], 8, 64);
        a[k] += __shfl_xor(a[k], 16, 64);
        a[k] += __shfl_xor(a[k], 32, 64);
    }

    float ss = 0.f;
    #pragma unroll
    for (int k = 0; k < 8; k++) {
        a[k] = (a[k] >= 0.f) ? a[k] : NEG_SLOPE * a[k];
        ss = fmaf(a[k], a[k], ss);
    }
    ss += __shfl_xor(ss, 1, 64);
    ss += __shfl_xor(ss, 2, 64);
    ss += __shfl_xor(ss, 4, 64);
    float inv = 1.f / fmaxf(sqrtf(ss), EPS_NRM);

    if (sub == 0) {
        uint4 o;
        o.x = (unsigned)f2bf(a[0] * inv) | ((unsigned)f2bf(a[1] * inv) << 16);
        o.y = (unsigned)f2bf(a[2] * inv) | ((unsigned)f2bf(a[3] * inv) << 16);
        o.z = (unsigned)f2bf(a[4] * inv) | ((unsigned)f2bf(a[5] * inv) << 16);
        o.w = (unsigned)f2bf(a[6] * inv) | ((unsigned)f2bf(a[7] * inv) << 16);
        *(uint4*)(pn + (size_t)row * D + fl * 8) = o;
    }
}

// one wave per batch element: sum 4 layer rows for the user once, then 3 item dots.
__global__ void score_kernel(const int* __restrict__ users,
                             const int* __restrict__ it0,
                             const int* __restrict__ it1,
                             const int* __restrict__ it2,
                             const ushort_t* __restrict__ p0,
                             const ushort_t* __restrict__ p1,
                             const ushort_t* __restrict__ p2,
                             const ushort_t* __restrict__ p3,
                             float* __restrict__ out) {
    int b    = blockIdx.x * 4 + (threadIdx.x >> 6);
    int lane = threadIdx.x & 63;
    if (b >= BATCH) return;
    int u = users[b];
    size_t uo = (size_t)u * D + lane;
    float uf = bf2f(p0[uo]) + bf2f(p1[uo]) + bf2f(p2[uo]) + bf2f(p3[uo]);

    int its[3];
    its[0] = it0[b]; its[1] = it1[b]; its[2] = it2[b];
    #pragma unroll
    for (int k = 0; k < 3; k++) {
        size_t io = (size_t)(NUM_USERS + its[k]) * D + lane;
        float itf = bf2f(p0[io]) + bf2f(p1[io]) + bf2f(p2[io]) + bf2f(p3[io]);
        float s = wave_sum64(uf * itf) * 0.0625f;
        if (lane == 0)
            out[k * BATCH + b] = 1.f / (1.f + expf(-s));
    }
}

extern "C" void kernel_launch(void* const* d_in, const int* in_sizes, int n_in,
                              void* d_out, int out_size, void* d_ws, size_t ws_size,
                              hipStream_t stream) {
    const int*   users  = (const int*)  d_in[0];
    const int*   adj    = (const int*)  d_in[1];
    const int*   weak   = (const int*)  d_in[2];
    const int*   strong = (const int*)  d_in[3];
    const int*   erows  = (const int*)  d_in[4];
    const int*   ecols  = (const int*)  d_in[5];
    const float* evals  = (const float*)d_in[6];
    const float* upref  = (const float*)d_in[7];
    const float* ipref  = (const float*)d_in[8];
    float* out = (float*)d_out;

    const size_t rowElems = (size_t)N_NODES * D;   // 9.6M

    char* base = (char*)d_ws;
    size_t off = 0;
    auto alloc = [&](size_t bytes) {
        char* p = base + off;
        off = (off + bytes + 255) & ~(size_t)255;
        return (void*)p;
    };
    ushort_t* p0     = (ushort_t*)alloc(rowElems * sizeof(ushort_t)); // 19.2 MB
    ushort_t* p1     = (ushort_t*)alloc(rowElems * sizeof(ushort_t)); // 19.2 MB
    ushort_t* p2     = (ushort_t*)alloc(rowElems * sizeof(ushort_t)); // 19.2 MB
    ushort_t* p3     = (ushort_t*)alloc(rowElems * sizeof(ushort_t)); // 19.2 MB
    int2*     es     = (int2*)    alloc((size_t)NNZ * sizeof(int2));  // 19.2 MB
    int*      ht     = (int*)     alloc((size_t)NH * sizeof(int));    // 0.6 MB
    int*      hoff   = (int*)     alloc((size_t)NH * sizeof(int));    // 0.6 MB
    int*      rowptr = (int*)     alloc((N_NODES + 1) * sizeof(int));
    int*      bsums  = (int*)     alloc(1024 * sizeof(int));
    // es_tmp aliases p2: p2 is first written by the layer-2 gather, which is
    // stream-ordered long after bucket_sort consumed est.
    int2*     est    = (int2*)p2;

    // ---- CSR build: bucket sort, zero global atomics ----
    bucket_hist   <<<NCHUNK, 256, 0, stream>>>(erows, ht);
    scan1_kernel  <<<NBH, 256, 0, stream>>>(ht, hoff, bsums, NH);
    scan3_kernel  <<<NBH, 256, 0, stream>>>(hoff, bsums, NH);
    bucket_scatter<<<NCHUNK, 512, 0, stream>>>(erows, ecols, evals, hoff, est);
    bucket_sort   <<<NBUCKET, 1024, 0, stream>>>(est, hoff, es, rowptr);

    // ---- GCN layers (no acc array; layers kept separately in bf16) ----
    init_kernel<<<(N_NODES + 3) / 4, 256, 0, stream>>>(upref, ipref, p0);
    gather_kernel<<<(N_NODES + 3) / 4, 256, 0, stream>>>(rowptr, es, p0, p1);
    gather_kernel<<<(N_NODES + 3) / 4, 256, 0, stream>>>(rowptr, es, p1, p2);
    gather_kernel<<<(N_NODES + 3) / 4, 256, 0, stream>>>(rowptr, es, p2, p3);

    score_kernel<<<(BATCH + 3) / 4, 256, 0, stream>>>(users, adj, weak, strong,
                                                      p0, p1, p2, p3, out);
}

// Round 14
// 390.112 us; speedup vs baseline: 1.0362x; 1.0362x over previous
//
#include <hip/hip_runtime.h>
#include <math.h>

#define D 64
#define NUM_USERS 100000
#define NUM_ITEMS 50000
#define N_NODES 150000   // NUM_USERS + NUM_ITEMS
#define NNZ 2400000
#define BATCH 8192
#define NEG_SLOPE 0.1f
#define EPS_NRM 1e-12f

// bucket geometry: bucket = row >> 8 (256 rows/bucket)
#define NBUCKET 586                 // ceil(150000/256)
#define NCHUNK  256
#define CH      9375                // NNZ / 256 exactly
#define NH      (NBUCKET * NCHUNK)  // 150016
#define NBH     (NH / 256)          // 586 scan blocks
#define CAP     6144                // LDS sorted-buffer capacity (mean 4096, ~32 sigma)
#define VSCALE  16383.f             // 14-bit val quantization

typedef unsigned short ushort_t;

__device__ __forceinline__ float wave_sum64(float v) {
    #pragma unroll
    for (int off = 32; off > 0; off >>= 1)
        v += __shfl_xor(v, off, 64);
    return v;
}

__device__ __forceinline__ int wave_sum64_i(int v) {
    #pragma unroll
    for (int off = 32; off > 0; off >>= 1)
        v += __shfl_xor(v, off, 64);
    return v;
}

__device__ __forceinline__ float bf2f(ushort_t u) {
    return __uint_as_float(((unsigned)u) << 16);
}
__device__ __forceinline__ ushort_t f2bf(float f) {
    unsigned x = __float_as_uint(f);
    unsigned r = (x + 0x7FFFu + ((x >> 16) & 1u)) >> 16;   // RNE
    return (ushort_t)r;
}

// ---------- CSR build: 2-level bucket sort, LDS int atomics only ----------

__global__ void bucket_hist(const int* __restrict__ rows, int* __restrict__ ht) {
    __shared__ int hist[NBUCKET];
    int c = blockIdx.x, tid = threadIdx.x;
    for (int b = tid; b < NBUCKET; b += 256) hist[b] = 0;
    __syncthreads();
    int base = c * CH;
    for (int i = tid; i < CH; i += 256)
        atomicAdd(&hist[rows[base + i] >> 8], 1);
    __syncthreads();
    for (int b = tid; b < NBUCKET; b += 256) ht[b * NCHUNK + c] = hist[b];
}

__global__ void scan1_kernel(const int* __restrict__ in, int* __restrict__ out,
                             int* __restrict__ bsums, int n) {
    int tid = threadIdx.x, gid = blockIdx.x * 256 + tid;
    int v = (gid < n) ? in[gid] : 0;
    int lane = tid & 63, w = tid >> 6;
    int s = v;
    #pragma unroll
    for (int off = 1; off < 64; off <<= 1) {
        int t = __shfl_up(s, off, 64);
        if (lane >= off) s += t;
    }
    __shared__ int wsum[4];
    if (lane == 63) wsum[w] = s;
    __syncthreads();
    if (tid == 0) {
        int a = 0;
        #pragma unroll
        for (int i = 0; i < 4; i++) { int t = wsum[i]; wsum[i] = a; a += t; }
    }
    __syncthreads();
    int incl = s + wsum[w];
    if (gid < n) out[gid] = incl - v;           // exclusive
    if (tid == 255) bsums[blockIdx.x] = incl;   // block total (unscanned)
}

// fused: each block reduces bsums[0..b) itself, then adds to its 256 elems
__global__ void scan3_kernel(int* __restrict__ out, const int* __restrict__ bsums, int n) {
    __shared__ int wtot[4];
    __shared__ int total;
    int b = blockIdx.x, tid = threadIdx.x;
    int lane = tid & 63, w = tid >> 6;
    int partial = 0;
    for (int i = tid; i < b; i += 256) partial += bsums[i];
    partial = wave_sum64_i(partial);
    if (lane == 0) wtot[w] = partial;
    __syncthreads();
    if (tid == 0) total = wtot[0] + wtot[1] + wtot[2] + wtot[3];
    __syncthreads();
    int gid = b * 256 + tid;
    if (gid < n) out[gid] += total;
}

__global__ void __launch_bounds__(512) bucket_scatter(
        const int* __restrict__ rows, const int* __restrict__ cols,
        const float* __restrict__ vals, const int* __restrict__ hoff,
        int2* __restrict__ est) {
    __shared__ int cur[NBUCKET];
    int c = blockIdx.x, tid = threadIdx.x;
    for (int b = tid; b < NBUCKET; b += 512) cur[b] = hoff[b * NCHUNK + c];
    __syncthreads();
    int base = c * CH;
    for (int i = tid; i < CH; i += 512) {
        int e = base + i;
        int r = rows[e];
        int pos = atomicAdd(&cur[r >> 8], 1);          // LDS int atomic
        est[pos] = make_int2(cols[e] | ((r & 255) << 18), __float_as_int(vals[e]));
    }
}

// one block per bucket: hist pass, scan, scatter into sorted LDS buffer with
// 14-bit val quantization (uint packed col|valq), coalesced dump. rowptr direct.
__global__ void __launch_bounds__(1024) bucket_sort(const int2* __restrict__ est,
                                                    const int* __restrict__ hoff,
                                                    unsigned* __restrict__ es,
                                                    int* __restrict__ rowptr) {
    __shared__ int      hist[256];
    __shared__ int      wsum[4];
    __shared__ unsigned outbuf[CAP];    // 24 KB
    int b = blockIdx.x, tid = threadIdx.x;
    int beg = hoff[b * NCHUNK];
    int end = (b == NBUCKET - 1) ? NNZ : hoff[(b + 1) * NCHUNK];
    if (tid < 256) hist[tid] = 0;
    __syncthreads();
    for (int i = beg + tid; i < end; i += 1024)
        atomicAdd(&hist[est[i].x >> 18], 1);
    __syncthreads();
    int excl = 0;
    if (tid < 256) {
        int v = hist[tid];
        int lane = tid & 63, w = tid >> 6;
        int s = v;
        #pragma unroll
        for (int off = 1; off < 64; off <<= 1) {
            int t = __shfl_up(s, off, 64);
            if (lane >= off) s += t;
        }
        if (lane == 63) wsum[w] = s;
        excl = s - v;
    }
    __syncthreads();
    if (tid == 0) {
        int a = 0;
        #pragma unroll
        for (int i = 0; i < 4; i++) { int t = wsum[i]; wsum[i] = a; a += t; }
    }
    __syncthreads();
    if (tid < 256) {
        excl += wsum[tid >> 6];
        int r = (b << 8) + tid;
        if (r <= N_NODES) rowptr[r] = beg + excl;
        hist[tid] = excl;           // reuse as cursor (bucket-relative)
    }
    __syncthreads();
    for (int i = beg + tid; i < end; i += 1024) {
        int2 kv = est[i];                                  // L2-warm re-read
        int d = atomicAdd(&hist[kv.x >> 18], 1);           // LDS int atomic
        float val = __int_as_float(kv.y);
        unsigned vq = (unsigned)(val * VSCALE + 0.5f);     // 14-bit quantize
        outbuf[d] = ((unsigned)kv.x & 0x3FFFFu) | (vq << 18);
    }
    __syncthreads();
    int n = end - beg;
    for (int i = tid; i < n; i += 1024)
        es[beg + i] = outbuf[i];                           // coalesced dump
}

// ---------- GCN ----------
__global__ void init_kernel(const float* __restrict__ upref,
                            const float* __restrict__ ipref,
                            ushort_t* __restrict__ p0) {
    int row  = blockIdx.x * 4 + (threadIdx.x >> 6);
    int lane = threadIdx.x & 63;
    if (row >= N_NODES) return;
    float x = (row < NUM_USERS) ? upref[(size_t)row * D + lane]
                                : ipref[(size_t)(row - NUM_USERS) * D + lane];
    x = (x >= 0.f) ? x : NEG_SLOPE * x;
    float norm = sqrtf(wave_sum64(x * x));
    float y = x / fmaxf(norm, EPS_NRM);
    p0[(size_t)row * D + lane] = f2bf(y);
}

// one wave per row; 8 edge-slots (sub = lane>>3), 8 features/lane (fl = lane&7);
// 2x unrolled; es entries are 4B packed col(18)|valq(14).
__global__ void gather_kernel(const int* __restrict__ rowptr,
                              const unsigned* __restrict__ es,
                              const ushort_t* __restrict__ p,
                              ushort_t* __restrict__ pn) {
    int row  = blockIdx.x * 4 + (threadIdx.x >> 6);
    int lane = threadIdx.x & 63;
    if (row >= N_NODES) return;
    int sub = lane >> 3;
    int fl  = lane & 7;
    int beg = rowptr[row], end = rowptr[row + 1];

    float a[8];
    #pragma unroll
    for (int k = 0; k < 8; k++) a[k] = 0.f;

    const float vs = 1.f / VSCALE;
    int e = beg + sub;
    while (e + 8 < end) {
        unsigned ev0 = es[e];
        unsigned ev1 = es[e + 8];
        const uint4 q0 = *(const uint4*)(p + (((ev0 & 0x3FFFFu) << 6) | (fl << 3)));
        const uint4 q1 = *(const uint4*)(p + (((ev1 & 0x3FFFFu) << 6) | (fl << 3)));
        float v0 = (float)(ev0 >> 18) * vs;
        float v1 = (float)(ev1 >> 18) * vs;
        a[0] = fmaf(v0, __uint_as_float(q0.x << 16),         a[0]);
        a[1] = fmaf(v0, __uint_as_float(q0.x & 0xFFFF0000u), a[1]);
        a[2] = fmaf(v0, __uint_as_float(q0.y << 16),         a[2]);
        a[3] = fmaf(v0, __uint_as_float(q0.y & 0xFFFF0000u), a[3]);
        a[4] = fmaf(v0, __uint_as_float(q0.z << 16),         a[4]);
        a[5] = fmaf(v0, __uint_as_float(q0.z & 0xFFFF0000u), a[5]);
        a[6] = fmaf(v0, __uint_as_float(q0.w << 16),         a[6]);
        a[7] = fmaf(v0, __uint_as_float(q0.w & 0xFFFF0000u), a[7]);
        a[0] = fmaf(v1, __uint_as_float(q1.x << 16),         a[0]);
        a[1] = fmaf(v1, __uint_as_float(q1.x & 0xFFFF0000u), a[1]);
        a[2] = fmaf(v1, __uint_as_float(q1.y << 16),         a[2]);
        a[3] = fmaf(v1, __uint_as_float(q1.y & 0xFFFF0000u), a[3]);
        a[4] = fmaf(v1, __uint_as_float(q1.z << 16),         a[4]);
        a[5] = fmaf(v1, __uint_as_float(q1.z & 0xFFFF0000u), a[5]);
        a[6] = fmaf(v1, __uint_as_float(q1.w << 16),         a[6]);
        a[7] = fmaf(v1, __uint_as_float(q1.w & 0xFFFF0000u), a[7]);
        e += 16;
    }
    if (e < end) {
        unsigned ev = es[e];
        const uint4 q = *(const uint4*)(p + (((ev & 0x3FFFFu) << 6) | (fl << 3)));
        float v = (float)(ev >> 18) * vs;
        a[0] = fmaf(v, __uint_as_float(q.x << 16),         a[0]);
        a[1] = fmaf(v, __uint_as_float(q.x & 0xFFFF0000u), a[1]);
        a[2] = fmaf(v, __uint_as_float(q.y << 16),         a[2]);
        a[3] = fmaf(v, __uint_as_float(q.y & 0xFFFF0000u), a[3]);
        a[4] = fmaf(v, __uint_as_float(q.z << 16),         a[4]);
        a[5] = fmaf(v, __uint_as_float(q.z & 0xFFFF0000u), a[5]);
        a[6] = fmaf(v, __uint_as_float(q.w << 16),         a[6]);
        a[7] = fmaf(v, __uint_as_float(q.w & 0xFFFF0000u), a[7]);
    }

    #pragma unroll
    for (int k = 0; k < 8; k++) {
        a[k] += __shfl_xor(a[k], 8, 64);
        a[k] += __shfl_xor(a[k], 16, 64);
        a[k] += __shfl_xor(a[k], 32, 64);
    }

    float ss = 0.f;
    #pragma unroll
    for (int k = 0; k < 8; k++) {
        a[k] = (a[k] >= 0.f) ? a[k] : NEG_SLOPE * a[k];
        ss = fmaf(a[k], a[k], ss);
    }
    ss += __shfl_xor(ss, 1, 64);
    ss += __shfl_xor(ss, 2, 64);
    ss += __shfl_xor(ss, 4, 64);
    float inv = 1.f / fmaxf(sqrtf(ss), EPS_NRM);

    if (sub == 0) {
        uint4 o;
        o.x = (unsigned)f2bf(a[0] * inv) | ((unsigned)f2bf(a[1] * inv) << 16);
        o.y = (unsigned)f2bf(a[2] * inv) | ((unsigned)f2bf(a[3] * inv) << 16);
        o.z = (unsigned)f2bf(a[4] * inv) | ((unsigned)f2bf(a[5] * inv) << 16);
        o.w = (unsigned)f2bf(a[6] * inv) | ((unsigned)f2bf(a[7] * inv) << 16);
        *(uint4*)(pn + (size_t)row * D + fl * 8) = o;
    }
}

// one wave per batch element: sum 4 layer rows for the user once, then 3 item dots.
__global__ void score_kernel(const int* __restrict__ users,
                             const int* __restrict__ it0,
                             const int* __restrict__ it1,
                             const int* __restrict__ it2,
                             const ushort_t* __restrict__ p0,
                             const ushort_t* __restrict__ p1,
                             const ushort_t* __restrict__ p2,
                             const ushort_t* __restrict__ p3,
                             float* __restrict__ out) {
    int b    = blockIdx.x * 4 + (threadIdx.x >> 6);
    int lane = threadIdx.x & 63;
    if (b >= BATCH) return;
    int u = users[b];
    size_t uo = (size_t)u * D + lane;
    float uf = bf2f(p0[uo]) + bf2f(p1[uo]) + bf2f(p2[uo]) + bf2f(p3[uo]);

    int its[3];
    its[0] = it0[b]; its[1] = it1[b]; its[2] = it2[b];
    #pragma unroll
    for (int k = 0; k < 3; k++) {
        size_t io = (size_t)(NUM_USERS + its[k]) * D + lane;
        float itf = bf2f(p0[io]) + bf2f(p1[io]) + bf2f(p2[io]) + bf2f(p3[io]);
        float s = wave_sum64(uf * itf) * 0.0625f;
        if (lane == 0)
            out[k * BATCH + b] = 1.f / (1.f + expf(-s));
    }
}

extern "C" void kernel_launch(void* const* d_in, const int* in_sizes, int n_in,
                              void* d_out, int out_size, void* d_ws, size_t ws_size,
                              hipStream_t stream) {
    const int*   users  = (const int*)  d_in[0];
    const int*   adj    = (const int*)  d_in[1];
    const int*   weak   = (const int*)  d_in[2];
    const int*   strong = (const int*)  d_in[3];
    const int*   erows  = (const int*)  d_in[4];
    const int*   ecols  = (const int*)  d_in[5];
    const float* evals  = (const float*)d_in[6];
    const float* upref  = (const float*)d_in[7];
    const float* ipref  = (const float*)d_in[8];
    float* out = (float*)d_out;

    const size_t rowElems = (size_t)N_NODES * D;   // 9.6M

    char* base = (char*)d_ws;
    size_t off = 0;
    auto alloc = [&](size_t bytes) {
        char* p = base + off;
        off = (off + bytes + 255) & ~(size_t)255;
        return (void*)p;
    };
    ushort_t* p0     = (ushort_t*)alloc(rowElems * sizeof(ushort_t)); // 19.2 MB
    ushort_t* p1     = (ushort_t*)alloc(rowElems * sizeof(ushort_t)); // 19.2 MB
    ushort_t* p2     = (ushort_t*)alloc(rowElems * sizeof(ushort_t)); // 19.2 MB
    ushort_t* p3     = (ushort_t*)alloc(rowElems * sizeof(ushort_t)); // 19.2 MB
    unsigned* es     = (unsigned*)alloc((size_t)NNZ * sizeof(unsigned)); // 9.6 MB
    int*      ht     = (int*)     alloc((size_t)NH * sizeof(int));    // 0.6 MB
    int*      hoff   = (int*)     alloc((size_t)NH * sizeof(int));    // 0.6 MB
    int*      rowptr = (int*)     alloc((N_NODES + 1) * sizeof(int));
    int*      bsums  = (int*)     alloc(1024 * sizeof(int));
    // es_tmp aliases p2: p2 is first written by the layer-2 gather, which is
    // stream-ordered long after bucket_sort consumed est.
    int2*     est    = (int2*)p2;

    // ---- CSR build: bucket sort, zero global atomics ----
    bucket_hist   <<<NCHUNK, 256, 0, stream>>>(erows, ht);
    scan1_kernel  <<<NBH, 256, 0, stream>>>(ht, hoff, bsums, NH);
    scan3_kernel  <<<NBH, 256, 0, stream>>>(hoff, bsums, NH);
    bucket_scatter<<<NCHUNK, 512, 0, stream>>>(erows, ecols, evals, hoff, est);
    bucket_sort   <<<NBUCKET, 1024, 0, stream>>>(est, hoff, es, rowptr);

    // ---- GCN layers (no acc array; layers kept separately in bf16) ----
    init_kernel<<<(N_NODES + 3) / 4, 256, 0, stream>>>(upref, ipref, p0);
    gather_kernel<<<(N_NODES + 3) / 4, 256, 0, stream>>>(rowptr, es, p0, p1);
    gather_kernel<<<(N_NODES + 3) / 4, 256, 0, stream>>>(rowptr, es, p1, p2);
    gather_kernel<<<(N_NODES + 3) / 4, 256, 0, stream>>>(rowptr, es, p2, p3);

    score_kernel<<<(BATCH + 3) / 4, 256, 0, stream>>>(users, adj, weak, strong,
                                                      p0, p1, p2, p3, out);
}